// Round 1
// baseline (265.132 us; speedup 1.0000x reference)
//
#include <hip/hip_runtime.h>
#include <hip/hip_bf16.h>

typedef __bf16 bf16x8 __attribute__((ext_vector_type(8)));
typedef float f32x4 __attribute__((ext_vector_type(4)));
using bf16 = __hip_bfloat16;

#define SEQ 2048
#define DM 1024
#define NH 16
#define DH 64
#define NBH 32
#define MR 4096  // B*S

static __device__ __forceinline__ void async_cp16(const void* gsrc, void* ldsdst) {
  __builtin_amdgcn_global_load_lds((__attribute__((address_space(1))) void*)gsrc,
                                   (__attribute__((address_space(3))) void*)ldsdst, 16, 0, 0);
}

static __device__ __forceinline__ unsigned short f2bfu(float f) {
  bf16 h = __float2bfloat16(f);
  unsigned short u; __builtin_memcpy(&u, &h, 2); return u;
}

// ---------------- cast hidden_states to bf16 ----------------
__global__ __launch_bounds__(256) void cast_x(const float* __restrict__ X, bf16* __restrict__ Xb) {
  long g = ((long)blockIdx.x * 256 + threadIdx.x) * 8;
  float4 a = *(const float4*)(X + g);
  float4 b = *(const float4*)(X + g + 4);
  unsigned short u[8];
  u[0]=f2bfu(a.x); u[1]=f2bfu(a.y); u[2]=f2bfu(a.z); u[3]=f2bfu(a.w);
  u[4]=f2bfu(b.x); u[5]=f2bfu(b.y); u[6]=f2bfu(b.z); u[7]=f2bfu(b.w);
  uint4 o; __builtin_memcpy(&o, u, 16);
  *(uint4*)(Xb + g) = o;
}

// ---------------- transpose+cast weights: Wt[n][k] = W[k][n] ----------------
struct WPtrs { const float* w[6]; };

__global__ __launch_bounds__(256) void transpose_cast_w(WPtrs wp, bf16* __restrict__ WtAll) {
  const int z = blockIdx.z;
  const float* W = wp.w[z];
  bf16* Wt = WtAll + (long)z * DM * DM;
  __shared__ float Ts[32][33];
  int n0 = blockIdx.x * 32, k0 = blockIdx.y * 32;
  int tx = threadIdx.x, ty = threadIdx.y;
#pragma unroll
  for (int it = 0; it < 4; ++it)
    Ts[ty + 8*it][tx] = W[(long)(k0 + ty + 8*it) * DM + n0 + tx];
  __syncthreads();
#pragma unroll
  for (int it = 0; it < 4; ++it)
    Wt[(long)(n0 + ty + 8*it) * DM + k0 + tx] = __float2bfloat16(Ts[tx][ty + 8*it]);
}

// ---------------- shared GEMM core: 128x128 tile, BK=32, m97 structure ----------------
static __device__ __forceinline__ void gemm_core(
    const bf16* __restrict__ A, const bf16* __restrict__ Bt,
    bf16* As, bf16* Bs, f32x4 (&acc)[4][4], int m0, int n0, int tid)
{
  const int wave = tid >> 6, lane = tid & 63, l15 = lane & 15, l4 = lane >> 4;
  const int wm = wave >> 1, wn = wave & 1;
  for (int k0 = 0; k0 < DM; k0 += 32) {
    __syncthreads();
    {
      int c0 = tid, c1 = 256 + tid;
      async_cp16(A  + (long)(m0 + (c0 >> 2)) * DM + k0 + (c0 & 3) * 8, As + wave * 64 * 8);
      async_cp16(A  + (long)(m0 + (c1 >> 2)) * DM + k0 + (c1 & 3) * 8, As + (256 + wave * 64) * 8);
      async_cp16(Bt + (long)(n0 + (c0 >> 2)) * DM + k0 + (c0 & 3) * 8, Bs + wave * 64 * 8);
      async_cp16(Bt + (long)(n0 + (c1 >> 2)) * DM + k0 + (c1 & 3) * 8, Bs + (256 + wave * 64) * 8);
    }
    __syncthreads();
    bf16x8 af[4], bfr[4];
#pragma unroll
    for (int i = 0; i < 4; ++i) af[i]  = *(const bf16x8*)(As + (wm * 64 + i * 16 + l15) * 32 + l4 * 8);
#pragma unroll
    for (int j = 0; j < 4; ++j) bfr[j] = *(const bf16x8*)(Bs + (wn * 64 + j * 16 + l15) * 32 + l4 * 8);
#pragma unroll
    for (int i = 0; i < 4; ++i)
#pragma unroll
      for (int j = 0; j < 4; ++j)
        acc[i][j] = __builtin_amdgcn_mfma_f32_16x16x32_bf16(af[i], bfr[j], acc[i][j], 0, 0, 0);
  }
}

// ---------------- projection GEMM: 5 heads-split outputs ----------------
struct ProjArgs {
  const bf16* Bt[5];
  const float* bias[5];
  bf16* out[5];
};

__global__ __launch_bounds__(256) void gemm_proj(const bf16* __restrict__ A, ProjArgs p) {
  __shared__ alignas(16) bf16 As[128 * 32];
  __shared__ alignas(16) bf16 Bs[128 * 32];
  const int z = blockIdx.z;
  const int tid = threadIdx.x;
  const int m0 = blockIdx.y * 128, n0 = blockIdx.x * 128;
  f32x4 acc[4][4] = {};
  gemm_core(A, p.Bt[z], As, Bs, acc, m0, n0, tid);
  const int wave = tid >> 6, lane = tid & 63, l15 = lane & 15, l4 = lane >> 4;
  const int wm = wave >> 1, wn = wave & 1;
  const float scale = (z == 0) ? 0.125f : 1.0f;   // q pre-scaled by 1/sqrt(DH)
  const float* bias = p.bias[z];
  bf16* out = p.out[z];
  float bv[4];
#pragma unroll
  for (int j = 0; j < 4; ++j) bv[j] = bias[n0 + wn * 64 + j * 16 + l15];
#pragma unroll
  for (int i = 0; i < 4; ++i)
#pragma unroll
    for (int j = 0; j < 4; ++j)
#pragma unroll
      for (int r = 0; r < 4; ++r) {
        int m = m0 + wm * 64 + i * 16 + l4 * 4 + r;
        int n = n0 + wn * 64 + j * 16 + l15;
        float v = (acc[i][j][r] + bv[j]) * scale;
        int b = m >> 11, s = m & 2047, hh = n >> 6, d = n & 63;
        long idx;
        if (z >= 2) idx = ((long)((b * NH + hh) * DH + d)) * SEQ + s;       // transposed [BH][DH][S]
        else        idx = ((long)((b * NH + hh) * SEQ + s)) * DH + d;       // natural   [BH][S][DH]
        out[idx] = __float2bfloat16(v);
      }
}

// ---------------- final GEMM: ctx2 @ Wd + bd -> fp32 ----------------
__global__ __launch_bounds__(256) void gemm_out(const bf16* __restrict__ A, const bf16* __restrict__ Bt,
                                                const float* __restrict__ bias, float* __restrict__ out) {
  __shared__ alignas(16) bf16 As[128 * 32];
  __shared__ alignas(16) bf16 Bs[128 * 32];
  const int tid = threadIdx.x;
  const int m0 = blockIdx.y * 128, n0 = blockIdx.x * 128;
  f32x4 acc[4][4] = {};
  gemm_core(A, Bt, As, Bs, acc, m0, n0, tid);
  const int wave = tid >> 6, lane = tid & 63, l15 = lane & 15, l4 = lane >> 4;
  const int wm = wave >> 1, wn = wave & 1;
  float bv[4];
#pragma unroll
  for (int j = 0; j < 4; ++j) bv[j] = bias[n0 + wn * 64 + j * 16 + l15];
#pragma unroll
  for (int i = 0; i < 4; ++i)
#pragma unroll
    for (int j = 0; j < 4; ++j)
#pragma unroll
      for (int r = 0; r < 4; ++r) {
        int m = m0 + wm * 64 + i * 16 + l4 * 4 + r;
        int n = n0 + wn * 64 + j * 16 + l15;
        out[(long)m * DM + n] = acc[i][j][r] + bv[j];
      }
}

// ---------------- flash attention (causal), MFMA, softmax in registers ----------------
__global__ __launch_bounds__(256) void attn_kernel(
    const bf16* __restrict__ q,    // [BH][S][DH], pre-scaled by 1/8
    const bf16* __restrict__ k1,   // [BH][S][DH]
    const bf16* __restrict__ v1t,  // [BH][DH][S]
    bf16* __restrict__ ctx1)       // [BH][S][DH]
{
  const int qb = blockIdx.x, bh = blockIdx.y;
  const int tid = threadIdx.x, wave = tid >> 6, lane = tid & 63;
  const int l15 = lane & 15, l4 = lane >> 4;
  const int Q0 = qb * 64;
  const bf16* qp = q   + (long)bh * SEQ * DH;
  const bf16* kp = k1  + (long)bh * SEQ * DH;
  const bf16* vp = v1t + (long)bh * DH * SEQ;
  bf16* op = ctx1 + (long)bh * SEQ * DH;

  __shared__ alignas(16) bf16 Qs[64 * 64];
  __shared__ alignas(16) bf16 Ks[64 * 64];
  __shared__ alignas(16) bf16 Vs[64 * 64];   // [dd][kv] (from v1t)
  __shared__ alignas(16) bf16 Ps[64 * 64];

  // stage Q once (pre-swizzled source; LDS linear; read applies same XOR)
  {
    int c = tid, r = c >> 3, p = c & 7;
    async_cp16(qp + (long)(Q0 + r) * DH + ((p ^ (r & 7)) * 8), (char*)Qs + wave * 64 * 16);
    c = 256 + tid; r = c >> 3; p = c & 7;
    async_cp16(qp + (long)(Q0 + r) * DH + ((p ^ (r & 7)) * 8), (char*)Qs + (256 + wave * 64) * 16);
  }

  f32x4 acc_o[4] = {};
  float m_run[4], l_run[4];
#pragma unroll
  for (int r = 0; r < 4; ++r) { m_run[r] = -__builtin_inff(); l_run[r] = 0.f; }

  for (int j = 0; j <= qb; ++j) {
    __syncthreads();
    const int kv0 = j * 64;
    {
      int c = tid, r = c >> 3, p = c & 7;
      async_cp16(kp + (long)(kv0 + r) * DH + ((p ^ (r & 7)) * 8), (char*)Ks + wave * 64 * 16);
      async_cp16(vp + (long)r * SEQ + kv0 + ((p ^ (r & 7)) * 8),  (char*)Vs + wave * 64 * 16);
      c = 256 + tid; r = c >> 3; p = c & 7;
      async_cp16(kp + (long)(kv0 + r) * DH + ((p ^ (r & 7)) * 8), (char*)Ks + (256 + wave * 64) * 16);
      async_cp16(vp + (long)r * SEQ + kv0 + ((p ^ (r & 7)) * 8),  (char*)Vs + (256 + wave * 64) * 16);
    }
    __syncthreads();

    // QK^T : wave owns q rows [16*wave, 16*wave+16)
    f32x4 sc[4] = {};
    bf16x8 aq[2];
#pragma unroll
    for (int h = 0; h < 2; ++h) {
      int row = 16 * wave + l15;
      int part = (4 * h + l4) ^ (row & 7);
      aq[h] = *(const bf16x8*)(Qs + row * 64 + part * 8);
    }
#pragma unroll
    for (int nb = 0; nb < 4; ++nb)
#pragma unroll
      for (int h = 0; h < 2; ++h) {
        int kr = nb * 16 + l15;
        int part = (4 * h + l4) ^ (kr & 7);
        bf16x8 bk = *(const bf16x8*)(Ks + kr * 64 + part * 8);
        sc[nb] = __builtin_amdgcn_mfma_f32_16x16x32_bf16(aq[h], bk, sc[nb], 0, 0, 0);
      }

    if (j == qb) {  // causal mask on diagonal tile
#pragma unroll
      for (int nb = 0; nb < 4; ++nb)
#pragma unroll
        for (int r = 0; r < 4; ++r) {
          int rowg = Q0 + 16 * wave + l4 * 4 + r;
          int colg = kv0 + nb * 16 + l15;
          if (colg > rowg) sc[nb][r] = -__builtin_inff();
        }
    }

    // row max over the 16 lanes sharing a row (l4 fixed)
    float sf[4];
#pragma unroll
    for (int r = 0; r < 4; ++r) {
      float v = fmaxf(fmaxf(sc[0][r], sc[1][r]), fmaxf(sc[2][r], sc[3][r]));
      v = fmaxf(v, __shfl_xor(v, 1));
      v = fmaxf(v, __shfl_xor(v, 2));
      v = fmaxf(v, __shfl_xor(v, 4));
      v = fmaxf(v, __shfl_xor(v, 8));
      float mnew = fmaxf(m_run[r], v);
      sf[r] = __expf(m_run[r] - mnew);
      m_run[r] = mnew;
    }

    // p = exp(s - m); write Ps (swizzled); accumulate tile sums
    float ts[4] = {0.f, 0.f, 0.f, 0.f};
#pragma unroll
    for (int nb = 0; nb < 4; ++nb)
#pragma unroll
      for (int r = 0; r < 4; ++r) {
        float pv = __expf(sc[nb][r] - m_run[r]);   // exp(-inf - finite) = 0
        ts[r] += pv;
        int row = 16 * wave + l4 * 4 + r;
        int col = nb * 16 + l15;
        Ps[row * 64 + ((col >> 3) ^ (row & 7)) * 8 + (col & 7)] = __float2bfloat16(pv);
      }
#pragma unroll
    for (int r = 0; r < 4; ++r) {
      float v = ts[r];
      v += __shfl_xor(v, 1);
      v += __shfl_xor(v, 2);
      v += __shfl_xor(v, 4);
      v += __shfl_xor(v, 8);
      l_run[r] = l_run[r] * sf[r] + v;
      acc_o[0][r] *= sf[r]; acc_o[1][r] *= sf[r]; acc_o[2][r] *= sf[r]; acc_o[3][r] *= sf[r];
    }

    // PV (Ps rows are wave-private: no barrier needed, lgkmcnt ordering suffices)
    bf16x8 pa[2];
#pragma unroll
    for (int h = 0; h < 2; ++h) {
      int row = 16 * wave + l15;
      int part = (4 * h + l4) ^ (row & 7);
      pa[h] = *(const bf16x8*)(Ps + row * 64 + part * 8);
    }
#pragma unroll
    for (int nb = 0; nb < 4; ++nb)
#pragma unroll
      for (int h = 0; h < 2; ++h) {
        int dd = nb * 16 + l15;
        int part = (4 * h + l4) ^ (dd & 7);
        bf16x8 vb = *(const bf16x8*)(Vs + dd * 64 + part * 8);
        acc_o[nb] = __builtin_amdgcn_mfma_f32_16x16x32_bf16(pa[h], vb, acc_o[nb], 0, 0, 0);
      }
  }

  // epilogue: normalize and store ctx1
#pragma unroll
  for (int nb = 0; nb < 4; ++nb)
#pragma unroll
    for (int r = 0; r < 4; ++r) {
      int row = Q0 + 16 * wave + l4 * 4 + r;
      int dd = nb * 16 + l15;
      op[(long)row * DH + dd] = __float2bfloat16(acc_o[nb][r] / l_run[r]);
    }
}

// ---------------- M[b,h] = k2^T v2  (64x64 per head) ----------------
__global__ __launch_bounds__(256) void m_kernel(
    const bf16* __restrict__ k2t, const bf16* __restrict__ v2t, float* __restrict__ Mbuf)
{
  const int scx = blockIdx.x;  // s chunk 0..7 (256 each)
  const int bh = blockIdx.y;
  const int tid = threadIdx.x, wave = tid >> 6, lane = tid & 63, l15 = lane & 15, l4 = lane >> 4;
  const bf16* kp = k2t + (long)bh * DH * SEQ;
  const bf16* vp = v2t + (long)bh * DH * SEQ;
  __shared__ alignas(16) bf16 K2s[64 * 32];
  __shared__ alignas(16) bf16 V2s[64 * 32];
  f32x4 acc[4] = {};
  const int s0 = scx * 256;
  for (int kk = 0; kk < 256; kk += 32) {
    __syncthreads();
    {
      int c = tid, r = c >> 2, p = c & 3;
      async_cp16(kp + (long)r * SEQ + s0 + kk + p * 8, K2s + wave * 64 * 8);
      async_cp16(vp + (long)r * SEQ + s0 + kk + p * 8, V2s + wave * 64 * 8);
    }
    __syncthreads();
    int arow = 16 * wave + l15;
    bf16x8 a = *(const bf16x8*)(K2s + arow * 32 + l4 * 8);
#pragma unroll
    for (int nb = 0; nb < 4; ++nb) {
      int col = nb * 16 + l15;
      bf16x8 b = *(const bf16x8*)(V2s + col * 32 + l4 * 8);
      acc[nb] = __builtin_amdgcn_mfma_f32_16x16x32_bf16(a, b, acc[nb], 0, 0, 0);
    }
  }
  float* Mp = Mbuf + (long)bh * 4096;
#pragma unroll
  for (int nb = 0; nb < 4; ++nb)
#pragma unroll
    for (int r = 0; r < 4; ++r) {
      int row = 16 * wave + l4 * 4 + r;
      int col = nb * 16 + l15;
      atomicAdd(Mp + row * 64 + col, acc[nb][r]);
    }
}

// ---------------- ctx2[b,s,(h,d')] = sum_d ctx1[b,h,s,d] * M[b,h,d,d'] ----------------
__global__ __launch_bounds__(256) void ctx2_kernel(
    const bf16* __restrict__ ctx1, const float* __restrict__ Mbuf, bf16* __restrict__ ctx2)
{
  const int sb = blockIdx.x;   // 0..31
  const int bh = blockIdx.y;
  const int b = bh >> 4, h = bh & 15;
  const int tid = threadIdx.x;
  __shared__ float Ms[4096];
  __shared__ alignas(16) bf16 C1[64 * 72];
  const float* Mp = Mbuf + (long)bh * 4096;
#pragma unroll
  for (int i = 0; i < 4; ++i)
    *(float4*)(Ms + (i * 256 + tid) * 4) = *(const float4*)(Mp + (i * 256 + tid) * 4);
  const bf16* c1p = ctx1 + ((long)bh * SEQ + sb * 64) * DH;
#pragma unroll
  for (int i = 0; i < 2; ++i) {
    int c = i * 256 + tid, r = c >> 3, p = c & 7;
    *(bf16x8*)(C1 + r * 72 + p * 8) = *(const bf16x8*)(c1p + r * DH + p * 8);
  }
  __syncthreads();
  const int row = tid >> 2, qtr = tid & 3;
  float acc[16] = {};
  for (int d = 0; d < 64; ++d) {
    float a = __bfloat162float(C1[row * 72 + d]);
    const float* mrow = Ms + d * 64 + qtr * 16;
#pragma unroll
    for (int i = 0; i < 16; ++i) acc[i] += a * mrow[i];
  }
  bf16* o = ctx2 + ((long)(b * SEQ) + sb * 64 + row) * DM + h * DH + qtr * 16;
#pragma unroll
  for (int i = 0; i < 16; ++i) o[i] = __float2bfloat16(acc[i]);
}

// ---------------- launch ----------------
extern "C" void kernel_launch(void* const* d_in, const int* in_sizes, int n_in,
                              void* d_out, int out_size, void* d_ws, size_t ws_size,
                              hipStream_t stream) {
  (void)in_sizes; (void)n_in; (void)out_size; (void)ws_size;
  const float* X = (const float*)d_in[0];
  const float* W[6]    = {(const float*)d_in[1], (const float*)d_in[3], (const float*)d_in[5],
                          (const float*)d_in[7], (const float*)d_in[9], (const float*)d_in[11]};
  const float* bias[6] = {(const float*)d_in[2], (const float*)d_in[4], (const float*)d_in[6],
                          (const float*)d_in[8], (const float*)d_in[10], (const float*)d_in[12]};

  char* ws = (char*)d_ws;
  bf16* Xb  = (bf16*)(ws);                 // 8 MB  (also reused as ctx2 after proj GEMM done)
  bf16* Wt  = (bf16*)(ws + (8L  << 20));   // 12 MB (6 x 2MB)
  bf16* qB  = (bf16*)(ws + (20L << 20));   // 8 MB  [BH][S][DH]
  bf16* k1B = (bf16*)(ws + (28L << 20));   // 8 MB  [BH][S][DH]
  bf16* k2t = (bf16*)(ws + (36L << 20));   // 8 MB  [BH][DH][S]
  bf16* v1t = (bf16*)(ws + (44L << 20));   // 8 MB  [BH][DH][S]
  bf16* v2t = (bf16*)(ws + (52L << 20));   // 8 MB  [BH][DH][S]
  bf16* c1  = (bf16*)(ws + (60L << 20));   // 8 MB  [BH][S][DH]
  float* Mb = (float*)(ws + (68L << 20));  // 512 KB
  bf16* c2  = Xb;                          // reuse: ctx2 [4096][1024]

  cast_x<<<2048, 256, 0, stream>>>(X, Xb);

  WPtrs wp; for (int z = 0; z < 6; ++z) wp.w[z] = W[z];
  transpose_cast_w<<<dim3(32, 32, 6), dim3(32, 8), 0, stream>>>(wp, Wt);

  ProjArgs pa;
  for (int z = 0; z < 5; ++z) { pa.Bt[z] = Wt + (long)z * DM * DM; pa.bias[z] = bias[z]; }
  pa.out[0] = qB; pa.out[1] = k1B; pa.out[2] = k2t; pa.out[3] = v1t; pa.out[4] = v2t;
  gemm_proj<<<dim3(8, 32, 5), 256, 0, stream>>>(Xb, pa);

  attn_kernel<<<dim3(32, 32), 256, 0, stream>>>(qB, k1B, v1t, c1);

  hipMemsetAsync(Mb, 0, (size_t)NBH * 4096 * 4, stream);
  m_kernel<<<dim3(8, 32), 256, 0, stream>>>(k2t, v2t, Mb);

  ctx2_kernel<<<dim3(32, 32), 256, 0, stream>>>(c1, Mb, c2);

  gemm_out<<<dim3(8, 32), 256, 0, stream>>>(c2, Wt + 5L * DM * DM, bias[5], (float*)d_out);
}

// Round 2
// 180.794 us; speedup vs baseline: 1.4665x; 1.4665x over previous
//
#include <hip/hip_runtime.h>
#include <hip/hip_bf16.h>

typedef __bf16 bf16x8 __attribute__((ext_vector_type(8)));
typedef float f32x4 __attribute__((ext_vector_type(4)));
using bf16 = __hip_bfloat16;

#define SEQ 2048
#define DM 1024
#define NH 16
#define DH 64
#define NBH 32
#define MR 4096  // B*S

static __device__ __forceinline__ void async_cp16(const void* gsrc, void* ldsdst) {
  __builtin_amdgcn_global_load_lds((__attribute__((address_space(1))) void*)gsrc,
                                   (__attribute__((address_space(3))) void*)ldsdst, 16, 0, 0);
}

static __device__ __forceinline__ unsigned short f2bfu(float f) {
  bf16 h = __float2bfloat16(f);
  unsigned short u; __builtin_memcpy(&u, &h, 2); return u;
}
static __device__ __forceinline__ unsigned int pack_bf2(float lo, float hi) {
  return (unsigned int)f2bfu(lo) | ((unsigned int)f2bfu(hi) << 16);
}

// ---------------- cast hidden_states to bf16 ----------------
__global__ __launch_bounds__(256) void cast_x(const float* __restrict__ X, bf16* __restrict__ Xb) {
  long g = ((long)blockIdx.x * 256 + threadIdx.x) * 8;
  float4 a = *(const float4*)(X + g);
  float4 b = *(const float4*)(X + g + 4);
  unsigned short u[8];
  u[0]=f2bfu(a.x); u[1]=f2bfu(a.y); u[2]=f2bfu(a.z); u[3]=f2bfu(a.w);
  u[4]=f2bfu(b.x); u[5]=f2bfu(b.y); u[6]=f2bfu(b.z); u[7]=f2bfu(b.w);
  uint4 o; __builtin_memcpy(&o, u, 16);
  *(uint4*)(Xb + g) = o;
}

// ---------------- transpose+cast weights: Wt[n][k] = W[k][n] ----------------
struct WPtrs { const float* w[6]; };

__global__ __launch_bounds__(256) void transpose_cast_w(WPtrs wp, bf16* __restrict__ WtAll) {
  const int z = blockIdx.z;
  const float* W = wp.w[z];
  bf16* Wt = WtAll + (long)z * DM * DM;
  __shared__ float Ts[32][33];
  int n0 = blockIdx.x * 32, k0 = blockIdx.y * 32;
  int tx = threadIdx.x, ty = threadIdx.y;
#pragma unroll
  for (int it = 0; it < 4; ++it)
    Ts[ty + 8*it][tx] = W[(long)(k0 + ty + 8*it) * DM + n0 + tx];
  __syncthreads();
#pragma unroll
  for (int it = 0; it < 4; ++it)
    Wt[(long)(n0 + ty + 8*it) * DM + k0 + tx] = __float2bfloat16(Ts[tx][ty + 8*it]);
}

// ---------------- shared GEMM core: 128x128 tile, BK=32, m97 structure ----------------
static __device__ __forceinline__ void gemm_core(
    const bf16* __restrict__ A, const bf16* __restrict__ Bt,
    bf16* As, bf16* Bs, f32x4 (&acc)[4][4], int m0, int n0, int tid)
{
  const int wave = tid >> 6, lane = tid & 63, l15 = lane & 15, l4 = lane >> 4;
  const int wm = wave >> 1, wn = wave & 1;
  for (int k0 = 0; k0 < DM; k0 += 32) {
    __syncthreads();
    {
      int c0 = tid, c1 = 256 + tid;
      async_cp16(A  + (long)(m0 + (c0 >> 2)) * DM + k0 + (c0 & 3) * 8, As + wave * 64 * 8);
      async_cp16(A  + (long)(m0 + (c1 >> 2)) * DM + k0 + (c1 & 3) * 8, As + (256 + wave * 64) * 8);
      async_cp16(Bt + (long)(n0 + (c0 >> 2)) * DM + k0 + (c0 & 3) * 8, Bs + wave * 64 * 8);
      async_cp16(Bt + (long)(n0 + (c1 >> 2)) * DM + k0 + (c1 & 3) * 8, Bs + (256 + wave * 64) * 8);
    }
    __syncthreads();
    bf16x8 af[4], bfr[4];
#pragma unroll
    for (int i = 0; i < 4; ++i) af[i]  = *(const bf16x8*)(As + (wm * 64 + i * 16 + l15) * 32 + l4 * 8);
#pragma unroll
    for (int j = 0; j < 4; ++j) bfr[j] = *(const bf16x8*)(Bs + (wn * 64 + j * 16 + l15) * 32 + l4 * 8);
#pragma unroll
    for (int i = 0; i < 4; ++i)
#pragma unroll
      for (int j = 0; j < 4; ++j)
        acc[i][j] = __builtin_amdgcn_mfma_f32_16x16x32_bf16(af[i], bfr[j], acc[i][j], 0, 0, 0);
  }
}

// ---------------- projection GEMM: 5 heads-split outputs ----------------
struct ProjArgs {
  const bf16* Bt[5];
  const float* bias[5];
  bf16* out[5];
};

__global__ __launch_bounds__(256) void gemm_proj(const bf16* __restrict__ A, ProjArgs p) {
  __shared__ alignas(16) bf16 As[128 * 32];
  __shared__ alignas(16) bf16 Bs[128 * 32];
  const int z = blockIdx.z;
  const int tid = threadIdx.x;
  const int m0 = blockIdx.y * 128, n0 = blockIdx.x * 128;
  f32x4 acc[4][4] = {};
  gemm_core(A, p.Bt[z], As, Bs, acc, m0, n0, tid);
  const int wave = tid >> 6, lane = tid & 63, l15 = lane & 15, l4 = lane >> 4;
  const int wm = wave >> 1, wn = wave & 1;
  // q pre-scaled by (1/sqrt(DH)) * log2(e) so attention softmax can run in exp2 domain
  const float scale = (z == 0) ? 0.125f * 1.44269504f : 1.0f;
  const float* bias = p.bias[z];
  bf16* out = p.out[z];
  float bv[4];
#pragma unroll
  for (int j = 0; j < 4; ++j) bv[j] = bias[n0 + wn * 64 + j * 16 + l15];
#pragma unroll
  for (int i = 0; i < 4; ++i)
#pragma unroll
    for (int j = 0; j < 4; ++j)
#pragma unroll
      for (int r = 0; r < 4; ++r) {
        int m = m0 + wm * 64 + i * 16 + l4 * 4 + r;
        int n = n0 + wn * 64 + j * 16 + l15;
        float v = (acc[i][j][r] + bv[j]) * scale;
        int b = m >> 11, s = m & 2047, hh = n >> 6, d = n & 63;
        long idx;
        if (z >= 2) idx = ((long)((b * NH + hh) * DH + d)) * SEQ + s;       // transposed [BH][DH][S]
        else        idx = ((long)((b * NH + hh) * SEQ + s)) * DH + d;       // natural   [BH][S][DH]
        out[idx] = __float2bfloat16(v);
      }
}

// ---------------- final GEMM: ctx2 @ Wd + bd -> fp32 ----------------
__global__ __launch_bounds__(256) void gemm_out(const bf16* __restrict__ A, const bf16* __restrict__ Bt,
                                                const float* __restrict__ bias, float* __restrict__ out) {
  __shared__ alignas(16) bf16 As[128 * 32];
  __shared__ alignas(16) bf16 Bs[128 * 32];
  const int tid = threadIdx.x;
  const int m0 = blockIdx.y * 128, n0 = blockIdx.x * 128;
  f32x4 acc[4][4] = {};
  gemm_core(A, Bt, As, Bs, acc, m0, n0, tid);
  const int wave = tid >> 6, lane = tid & 63, l15 = lane & 15, l4 = lane >> 4;
  const int wm = wave >> 1, wn = wave & 1;
  float bv[4];
#pragma unroll
  for (int j = 0; j < 4; ++j) bv[j] = bias[n0 + wn * 64 + j * 16 + l15];
#pragma unroll
  for (int i = 0; i < 4; ++i)
#pragma unroll
    for (int j = 0; j < 4; ++j)
#pragma unroll
      for (int r = 0; r < 4; ++r) {
        int m = m0 + wm * 64 + i * 16 + l4 * 4 + r;
        int n = n0 + wn * 64 + j * 16 + l15;
        out[(long)m * DM + n] = acc[i][j][r] + bv[j];
      }
}

// ---------------- M[b,h] = k2^T v2  (64x64 per head, f32 atomics) ----------------
__global__ __launch_bounds__(256) void m_kernel(
    const bf16* __restrict__ k2t, const bf16* __restrict__ v2t, float* __restrict__ Mbuf)
{
  const int scx = blockIdx.x;  // s chunk 0..7 (256 each)
  const int bh = blockIdx.y;
  const int tid = threadIdx.x, wave = tid >> 6, lane = tid & 63, l15 = lane & 15, l4 = lane >> 4;
  const bf16* kp = k2t + (long)bh * DH * SEQ;
  const bf16* vp = v2t + (long)bh * DH * SEQ;
  __shared__ alignas(16) bf16 K2s[64 * 32];
  __shared__ alignas(16) bf16 V2s[64 * 32];
  f32x4 acc[4] = {};
  const int s0 = scx * 256;
  for (int kk = 0; kk < 256; kk += 32) {
    __syncthreads();
    {
      int c = tid, r = c >> 2, p = c & 3;
      async_cp16(kp + (long)r * SEQ + s0 + kk + p * 8, K2s + wave * 64 * 8);
      async_cp16(vp + (long)r * SEQ + s0 + kk + p * 8, V2s + wave * 64 * 8);
    }
    __syncthreads();
    int arow = 16 * wave + l15;
    bf16x8 a = *(const bf16x8*)(K2s + arow * 32 + l4 * 8);
#pragma unroll
    for (int nb = 0; nb < 4; ++nb) {
      int col = nb * 16 + l15;
      bf16x8 b = *(const bf16x8*)(V2s + col * 32 + l4 * 8);
      acc[nb] = __builtin_amdgcn_mfma_f32_16x16x32_bf16(a, b, acc[nb], 0, 0, 0);
    }
  }
  float* Mp = Mbuf + (long)bh * 4096;
#pragma unroll
  for (int nb = 0; nb < 4; ++nb)
#pragma unroll
    for (int r = 0; r < 4; ++r) {
      int row = 16 * wave + l4 * 4 + r;   // d  (k2 feature)
      int col = nb * 16 + l15;            // d' (v2 feature)
      atomicAdd(Mp + row * 64 + col, acc[nb][r]);
    }
}

// -------- cross-lane redistribution: acc layout (idx = 16nb+4*l4+r per lane) ->
// -------- B-frag layout (lane holds 8 consecutive idx = 32h+8*l4+j) ----------
static __device__ __forceinline__ void redist(const unsigned int (&pk)[4][2], bf16x8 (&pb)[2],
                                              int l4, int l15) {
#pragma unroll
  for (int h = 0; h < 2; ++h) {
    unsigned int w4[4];
#pragma unroll
    for (int w = 0; w < 4; ++w) {
      int src = l15 + 16 * (2 * (l4 & 1) + (w >> 1));
      unsigned int va = (unsigned int)__shfl((int)pk[2 * h][w & 1], src);
      unsigned int vb = (unsigned int)__shfl((int)pk[2 * h + 1][w & 1], src);
      w4[w] = (l4 & 2) ? vb : va;
    }
    __builtin_memcpy(&pb[h], w4, 16);
  }
}

// ---------------- fused flash attention + ctx2 = (softmax(QK^T)V1) @ M ----------------
// Per block: q-tile PAIR (31-qt, qt) of 64 rows each -> exactly 33 KV iterations/block.
// Swapped QK^T: lane owns one q-row; softmax in-lane + 2 shfl. P redistributed via shfl.
__global__ __launch_bounds__(256) void attn_fused(
    const bf16* __restrict__ q,    // [BH][S][DH], pre-scaled by log2e/8
    const bf16* __restrict__ k1,   // [BH][S][DH]
    const bf16* __restrict__ v1t,  // [BH][DH][S]
    const float* __restrict__ Mbuf,// [BH][64][64]  M[d][d'] = sum_s k2 v2
    bf16* __restrict__ ctx2)       // [B][S][DM] (head-interleaved)
{
  const int qpair = blockIdx.x;    // 0..15
  const int bh = blockIdx.y;
  const int bb = bh >> 4, hh = bh & 15;
  const int tid = threadIdx.x, wave = tid >> 6, lane = tid & 63;
  const int l15 = lane & 15, l4 = lane >> 4;
  const bf16* qp = q   + (long)bh * SEQ * DH;
  const bf16* kp = k1  + (long)bh * SEQ * DH;
  const bf16* vp = v1t + (long)bh * DH * SEQ;
  const float* Mp = Mbuf + (long)bh * 4096;

  __shared__ alignas(16) bf16 Ks[2][64 * 64];
  __shared__ alignas(16) bf16 Vs[2][64 * 64];

  // M^T fragments: mf[db'][h] element j = M[32h+8*l4+j][16*db'+l15]
  bf16x8 mf[4][2];
#pragma unroll
  for (int db = 0; db < 4; ++db)
#pragma unroll
    for (int h = 0; h < 2; ++h) {
      bf16x8 t;
#pragma unroll
      for (int j = 0; j < 8; ++j)
        t[j] = (__bf16)Mp[(32 * h + 8 * l4 + j) * 64 + 16 * db + l15];
      mf[db][h] = t;
    }

#define STAGE_KV(JJ, BUF) do {                                                     \
    int kv0_ = 64 * (JJ);                                                          \
    int c_ = tid, row_ = c_ >> 3, ch_ = c_ & 7;                                    \
    async_cp16(kp + (long)(kv0_ + row_) * DH + ((ch_ ^ (row_ & 7)) * 8),           \
               (char*)Ks[BUF] + wave * 1024);                                      \
    async_cp16(vp + (long)row_ * SEQ + kv0_ + ((ch_ ^ (row_ & 7)) * 8),            \
               (char*)Vs[BUF] + wave * 1024);                                      \
    c_ = tid + 256; row_ = c_ >> 3; ch_ = c_ & 7;                                  \
    async_cp16(kp + (long)(kv0_ + row_) * DH + ((ch_ ^ (row_ & 7)) * 8),           \
               (char*)Ks[BUF] + 4096 + wave * 1024);                               \
    async_cp16(vp + (long)row_ * SEQ + kv0_ + ((ch_ ^ (row_ & 7)) * 8),            \
               (char*)Vs[BUF] + 4096 + wave * 1024);                               \
  } while (0)

#pragma unroll 1
  for (int half = 0; half < 2; ++half) {
    const int tq = (half == 0) ? (31 - qpair) : qpair;   // big tile first
    const int Q0 = 64 * tq;
    const int qg = Q0 + 16 * wave + l15;   // this lane's q row
    const int jmax = tq;

    __syncthreads();            // protect LDS reuse from previous half's epilogue
    STAGE_KV(0, 0);

    bf16x8 aq[2];
#pragma unroll
    for (int h = 0; h < 2; ++h)
      aq[h] = *(const bf16x8*)(qp + (long)qg * DH + 32 * h + 8 * l4);

    float m_run = -__builtin_inff(), l_run = 0.f;
    f32x4 acc_o[4] = {};

    __syncthreads();            // stage(0) drained

#pragma unroll 1
    for (int j = 0; j <= jmax; ++j) {
      const int cur = j & 1;
      if (j < jmax) STAGE_KV(j + 1, cur ^ 1);

      // ---- QK^T (swapped): sc[nb] rows = kv, cols = q ----
      f32x4 sc[4] = {};
#pragma unroll
      for (int nb = 0; nb < 4; ++nb) {
        const bf16* krow = Ks[cur] + (16 * nb + l15) * 64;
#pragma unroll
        for (int h = 0; h < 2; ++h) {
          bf16x8 kf = *(const bf16x8*)(krow + (((4 * h + l4) ^ (l15 & 7)) * 8));
          sc[nb] = __builtin_amdgcn_mfma_f32_16x16x32_bf16(kf, aq[h], sc[nb], 0, 0, 0);
        }
      }

      if (j == jmax) {  // diagonal tile: causal mask (kv > q)
        const int kv0 = 64 * j;
#pragma unroll
        for (int nb = 0; nb < 4; ++nb)
#pragma unroll
          for (int r = 0; r < 4; ++r)
            if (kv0 + 16 * nb + 4 * l4 + r > qg) sc[nb][r] = -__builtin_inff();
      }

      // ---- softmax (per-lane row, exp2 domain) ----
      float tmax = -__builtin_inff();
#pragma unroll
      for (int nb = 0; nb < 4; ++nb)
#pragma unroll
        for (int r = 0; r < 4; ++r) tmax = fmaxf(tmax, sc[nb][r]);
      tmax = fmaxf(tmax, __shfl_xor(tmax, 16));
      tmax = fmaxf(tmax, __shfl_xor(tmax, 32));
      float mnew = fmaxf(m_run, tmax);
      float sf = __builtin_amdgcn_exp2f(m_run - mnew);
      m_run = mnew;

      float ssum = 0.f;
      unsigned int pk[4][2];
#pragma unroll
      for (int nb = 0; nb < 4; ++nb)
#pragma unroll
        for (int pr = 0; pr < 2; ++pr) {
          float p0 = __builtin_amdgcn_exp2f(sc[nb][2 * pr]     - mnew);
          float p1 = __builtin_amdgcn_exp2f(sc[nb][2 * pr + 1] - mnew);
          ssum += p0 + p1;
          pk[nb][pr] = pack_bf2(p0, p1);
        }
      ssum += __shfl_xor(ssum, 16);
      ssum += __shfl_xor(ssum, 32);
      l_run = l_run * sf + ssum;
#pragma unroll
      for (int db = 0; db < 4; ++db)
#pragma unroll
        for (int r = 0; r < 4; ++r) acc_o[db][r] *= sf;

      // ---- P -> B-frag layout, then PV ----
      bf16x8 pb[2];
      redist(pk, pb, l4, l15);
#pragma unroll
      for (int db = 0; db < 4; ++db) {
        const bf16* vrow = Vs[cur] + (16 * db + l15) * 64;
#pragma unroll
        for (int h = 0; h < 2; ++h) {
          bf16x8 vf = *(const bf16x8*)(vrow + (((4 * h + l4) ^ (l15 & 7)) * 8));
          acc_o[db] = __builtin_amdgcn_mfma_f32_16x16x32_bf16(vf, pb[h], acc_o[db], 0, 0, 0);
        }
      }
      __syncthreads();   // staged tile j+1 drained; buffers swappable
    }

    // ---- epilogue: ctx1 = acc/l ; ctx2_tile = ctx1 @ M  (8 MFMA) ----
    float invl = __builtin_amdgcn_rcpf(l_run);
    unsigned int ck[4][2];
#pragma unroll
    for (int db = 0; db < 4; ++db)
#pragma unroll
      for (int pr = 0; pr < 2; ++pr)
        ck[db][pr] = pack_bf2(acc_o[db][2 * pr] * invl, acc_o[db][2 * pr + 1] * invl);
    bf16x8 cb[2];
    redist(ck, cb, l4, l15);
    f32x4 o2[4] = {};
#pragma unroll
    for (int db = 0; db < 4; ++db)
#pragma unroll
      for (int h = 0; h < 2; ++h)
        o2[db] = __builtin_amdgcn_mfma_f32_16x16x32_bf16(mf[db][h], cb[h], o2[db], 0, 0, 0);

    // o2: row = d' = 16db+4*l4+r, col = q = l15 -> transpose via padded LDS, store coalesced
    bf16* Os = (bf16*)Ks;   // 64 x 72 (pad) = 9216 elems < 16KB region
#pragma unroll
    for (int db = 0; db < 4; ++db)
#pragma unroll
      for (int r = 0; r < 4; ++r)
        Os[(16 * wave + l15) * 72 + 16 * db + 4 * l4 + r] = __float2bfloat16(o2[db][r]);
    __syncthreads();
    {
      int rr = tid >> 2, cc = tid & 3;
      long obase = ((long)(bb * SEQ + Q0 + rr)) * DM + hh * DH + cc * 16;
      *(bf16x8*)(ctx2 + obase)     = *(const bf16x8*)(Os + rr * 72 + cc * 16);
      *(bf16x8*)(ctx2 + obase + 8) = *(const bf16x8*)(Os + rr * 72 + cc * 16 + 8);
    }
  }
#undef STAGE_KV
}

// ---------------- launch ----------------
extern "C" void kernel_launch(void* const* d_in, const int* in_sizes, int n_in,
                              void* d_out, int out_size, void* d_ws, size_t ws_size,
                              hipStream_t stream) {
  (void)in_sizes; (void)n_in; (void)out_size; (void)ws_size;
  const float* X = (const float*)d_in[0];
  const float* W[6]    = {(const float*)d_in[1], (const float*)d_in[3], (const float*)d_in[5],
                          (const float*)d_in[7], (const float*)d_in[9], (const float*)d_in[11]};
  const float* bias[6] = {(const float*)d_in[2], (const float*)d_in[4], (const float*)d_in[6],
                          (const float*)d_in[8], (const float*)d_in[10], (const float*)d_in[12]};

  char* ws = (char*)d_ws;
  bf16* Xb  = (bf16*)(ws);                 // 8 MB (reused as ctx2 after proj GEMM done)
  bf16* Wt  = (bf16*)(ws + (8L  << 20));   // 12 MB (6 x 2MB)
  bf16* qB  = (bf16*)(ws + (20L << 20));   // 8 MB  [BH][S][DH]
  bf16* k1B = (bf16*)(ws + (28L << 20));   // 8 MB  [BH][S][DH]
  bf16* k2t = (bf16*)(ws + (36L << 20));   // 8 MB  [BH][DH][S]
  bf16* v1t = (bf16*)(ws + (44L << 20));   // 8 MB  [BH][DH][S]
  bf16* v2t = (bf16*)(ws + (52L << 20));   // 8 MB  [BH][DH][S]
  float* Mb = (float*)(ws + (60L << 20));  // 512 KB
  bf16* c2  = Xb;                          // reuse: ctx2 [4096][1024]

  cast_x<<<2048, 256, 0, stream>>>(X, Xb);

  WPtrs wp; for (int z = 0; z < 6; ++z) wp.w[z] = W[z];
  transpose_cast_w<<<dim3(32, 32, 6), dim3(32, 8), 0, stream>>>(wp, Wt);

  ProjArgs pa;
  for (int z = 0; z < 5; ++z) { pa.Bt[z] = Wt + (long)z * DM * DM; pa.bias[z] = bias[z]; }
  pa.out[0] = qB; pa.out[1] = k1B; pa.out[2] = k2t; pa.out[3] = v1t; pa.out[4] = v2t;
  gemm_proj<<<dim3(8, 32, 5), 256, 0, stream>>>(Xb, pa);

  hipMemsetAsync(Mb, 0, (size_t)NBH * 4096 * 4, stream);
  m_kernel<<<dim3(8, 32), 256, 0, stream>>>(k2t, v2t, Mb);

  attn_fused<<<dim3(16, 32), 256, 0, stream>>>(qB, k1B, v1t, Mb, c2);

  gemm_out<<<dim3(8, 32), 256, 0, stream>>>(c2, Wt + 5L * DM * DM, bias[5], (float*)d_out);
}